// Round 5
// baseline (171.659 us; speedup 1.0000x reference)
//
#include <hip/hip_runtime.h>
#include <hip/hip_bf16.h>
#include <math.h>

#define B_ 4
#define N_ 32768
#define S_ 8192
#define K_ 16
#define CIN 64
#define COUT 128
#define MID_ 32
#define EPS_ 1e-5f
#define NTILE 2048   // (B_*S_)/16 epilogue tiles

typedef __attribute__((ext_vector_type(8))) short s16x8;
typedef __attribute__((ext_vector_type(4))) float f32x4;

// static scratch (written fully every call before being read)
__device__ ushort g_attn[(size_t)B_ * S_ * COUT];   // attn output, bf16, row-major
__device__ ushort g_sfeat[(size_t)B_ * S_ * CIN];   // gathered s_feat, bf16
__device__ float  g_part[NTILE * 8 * 2];            // GN partial sums per tile/group
__device__ float  g_stats[64];                      // GN mean/rstd per (b,g)
// fused weights: [0,2048) Wqa1 32x64; [2048,4096) Wka1 32x64; [4096,8192) Wpa1 32x128
__device__ float  g_fw[8192];

// hardware bf16 converts (v_cvt_pk_bf16_f32)
__device__ __forceinline__ uint pk2(float lo, float hi) {
  __hip_bfloat162 h = __float22bfloat162_rn(make_float2(lo, hi));
  return *(uint*)&h;
}
__device__ __forceinline__ ushort f2bf(float f) {
  __hip_bfloat16 h = __float2bfloat16(f);
  return *(ushort*)&h;
}
__device__ __forceinline__ int4 pack8(float4 a, float4 b) {
  int4 o;
  o.x = pk2(a.x, a.y); o.y = pk2(a.z, a.w);
  o.z = pk2(b.x, b.y); o.w = pk2(b.z, b.w);
  return o;
}
__device__ __forceinline__ f32x4 mfma16(s16x8 a, s16x8 b, f32x4 c) {
  return __builtin_amdgcn_mfma_f32_16x16x32_bf16(a, b, c, 0, 0, 0);
}
// weight B-frag reads, swizzled rows of 256B / 128B
__device__ __forceinline__ s16x8 ldw256(const ushort* W, int row, int g) {
  return *(const s16x8*)((const char*)W + row * 256 + ((g ^ (row & 7)) << 4));
}
__device__ __forceinline__ s16x8 ldw128(const ushort* W, int row, int g) {
  return *(const s16x8*)((const char*)W + row * 128 + ((g ^ (row & 7)) << 4));
}
__device__ __forceinline__ s16x8 ldfrag_g8(const float* p) {
  float4 a = *(const float4*)p, b = *(const float4*)(p + 4);
  union { int4 i; s16x8 s; } u;
  u.i = pack8(a, b);
  return u.s;
}
// store a C tile (16 cols at n-tile t) bf16 into 16x128 swizzled buffer, b16 writes
__device__ __forceinline__ void st16(char* bufb, int t, f32x4 c, int l, int cq,
                                     bool dorelu) {
  const int colp = (l & 15) + 16 * t;
  const int g = colp >> 3;
  const int off = (colp & 7) * 2;
  #pragma unroll
  for (int rr = 0; rr < 4; ++rr) {
    const int row = cq * 4 + rr;
    float v = dorelu ? fmaxf(c[rr], 0.f) : c[rr];
    *(ushort*)(bufb + row * 256 + ((g ^ (row & 7)) << 4) + off) = f2bf(v);
  }
}
// store 16x32 a1 tile (row stride 64B) with relu, b16 writes
__device__ __forceinline__ void st16_a1(char* bufb, int t, f32x4 c, int l, int cq) {
  const int colp = (l & 15) + 16 * t;   // 0..31
  const int g = colp >> 3;              // 0..3
  const int off = (colp & 7) * 2;
  #pragma unroll
  for (int rr = 0; rr < 4; ++rr) {
    const int row = cq * 4 + rr;
    *(ushort*)(bufb + row * 64 + ((g ^ (row & 3)) << 4) + off) =
        f2bf(fmaxf(c[rr], 0.f));
  }
}

struct PF { float4 f0, f1, f2, f3; float r0, r1, r2; };
__device__ __forceinline__ PF pfetch(const float* feats, const float* xyz,
                                     const int* idx_fps, int pid, int nid, int cq) {
  PF p;
  const int bb = pid >> 13;
  const float* fn = feats + ((size_t)bb * N_ + nid) * CIN + cq * 16;
  p.f0 = ((const float4*)fn)[0]; p.f1 = ((const float4*)fn)[1];
  p.f2 = ((const float4*)fn)[2]; p.f3 = ((const float4*)fn)[3];
  p.r0 = 0.f; p.r1 = 0.f; p.r2 = 0.f;
  if (cq == 0) {
    const float* xn = xyz + ((size_t)bb * N_ + nid) * 3;
    const float* xs = xyz + ((size_t)bb * N_ + idx_fps[pid]) * 3;
    p.r0 = xn[0] - xs[0]; p.r1 = xn[1] - xs[1]; p.r2 = xn[2] - xs[2];
  }
  return p;
}

// ---------------- Kernel 0: fused weights  Wa1 @ {Wq, Wk, Wp2} ---------------
__global__ __launch_bounds__(256) void k_fuse(
    const float* __restrict__ Wq, const float* __restrict__ Wk,
    const float* __restrict__ Wp2, const float* __restrict__ Wa1)
{
  const int t = blockIdx.x * 256 + threadIdx.x;   // 0..8191
  if (t < 2048) {
    int m = t >> 6, c = t & 63;
    float s = 0.f;
    for (int o = 0; o < COUT; ++o) s += Wa1[m * COUT + o] * Wq[o * CIN + c];
    g_fw[t] = s;
  } else if (t < 4096) {
    int u = t - 2048;
    int m = u >> 6, c = u & 63;
    float s = 0.f;
    for (int o = 0; o < COUT; ++o) s += Wa1[m * COUT + o] * Wk[o * CIN + c];
    g_fw[t] = s;
  } else {
    int u = t - 4096;
    int m = u >> 7, c = u & 127;
    float s = 0.f;
    for (int o = 0; o < COUT; ++o) s += Wa1[m * COUT + o] * Wp2[o * COUT + c];
    g_fw[t] = s;
  }
}

// ---------------- Kernel 1: attention core (P=2 points per iteration) -------
__global__ __launch_bounds__(512, 1) void k_attn(
    const float* __restrict__ xyz, const float* __restrict__ feats,
    const int* __restrict__ idx_fps, const int* __restrict__ idx_knn,
    const float* __restrict__ Wv, const float* __restrict__ Wp1,
    const float* __restrict__ Wp2, const float* __restrict__ Wa2,
    float* __restrict__ out_xyz)
{
  __shared__ ushort lWv[COUT * CIN];     // 16 KB, 128B rows swz
  __shared__ ushort lWp1[COUT * 8];      // 2 KB, 16B rows linear
  __shared__ ushort lWp2[COUT * COUT];   // 32 KB, 256B rows swz
  __shared__ ushort lWka1[MID_ * CIN];   // 4 KB, 128B rows swz (holds -Wka1)
  __shared__ ushort lWpa1[MID_ * COUT];  // 8 KB, 256B rows swz
  __shared__ ushort sbuf[8 * 5120];      // per wave 10KB: 2x4KB nfeat/t1 + 2x1KB a1

  const int tid = threadIdx.x;
  const int w = tid >> 6, l = tid & 63;
  const int r = l & 15, cq = l >> 4;

  for (int i = tid; i < COUT * CIN / 2; i += 512) {
    int row = i >> 5; int kp = (i & 31) * 2;
    int g = kp >> 3;
    *(uint*)((char*)lWv + row * 128 + ((g ^ (row & 7)) << 4) + (kp & 7) * 2)
        = pk2(Wv[row * CIN + kp], Wv[row * CIN + kp + 1]);
  }
  { // Wp1 padded: 128 rows x 4 pairs = 512
    int row = tid >> 2; int kp = (tid & 3) * 2;
    float lo = (kp < 3) ? Wp1[row * 3 + kp] : 0.f;
    float hi = (kp + 1 < 3) ? Wp1[row * 3 + kp + 1] : 0.f;
    *(uint*)((char*)lWp1 + row * 16 + kp * 2) = pk2(lo, hi);
  }
  for (int i = tid; i < COUT * CIN; i += 512) {
    int row = i >> 6; int kp = (i & 63) * 2;
    int g = kp >> 3;
    *(uint*)((char*)lWp2 + row * 256 + ((g ^ (row & 7)) << 4) + (kp & 7) * 2)
        = pk2(Wp2[row * COUT + kp], Wp2[row * COUT + kp + 1]);
  }
  for (int i = tid; i < MID_ * CIN / 2; i += 512) {   // -Wka1
    int row = i >> 5; int kp = (i & 31) * 2;
    int g = kp >> 3;
    const float* src = g_fw + 2048 + row * CIN + kp;
    *(uint*)((char*)lWka1 + row * 128 + ((g ^ (row & 7)) << 4) + (kp & 7) * 2)
        = pk2(-src[0], -src[1]);
  }
  for (int i = tid; i < MID_ * COUT / 2; i += 512) {  // Wpa1
    int row = i >> 6; int kp = (i & 63) * 2;
    int g = kp >> 3;
    const float* src = g_fw + 4096 + row * COUT + kp;
    *(uint*)((char*)lWpa1 + row * 256 + ((g ^ (row & 7)) << 4) + (kp & 7) * 2)
        = pk2(src[0], src[1]);
  }

  // register-resident B-frags: Wa2 (8 n-tiles)
  s16x8 fWa2[8];
  #pragma unroll
  for (int t = 0; t < 8; ++t)
    fWa2[t] = ldfrag_g8(Wa2 + (16 * t + r) * MID_ + cq * 8);

  __syncthreads();

  char* bufb = (char*)(sbuf + w * 5120);
  char* buf0 = bufb;
  char* buf1 = bufb + 4096;
  char* bufa0 = bufb + 8192;
  char* bufa1 = bufb + 9216;
  const int pid0 = (blockIdx.x * 8 + w) * 16;

  // ---- prologue: stage sfeat (row = point), qa1 GEMM for 16 points ----
  {
    const int p = pid0 + r;
    const int bb = p >> 13;
    const int si = idx_fps[p];
    const float* fs = feats + ((size_t)bb * N_ + si) * CIN;
    #pragma unroll
    for (int j = 0; j < 2; ++j) {
      int g = cq * 2 + j;
      int4 pks = pack8(*(const float4*)(fs + g * 8), *(const float4*)(fs + g * 8 + 4));
      *(int4*)(buf0 + r * 128 + ((g ^ (r & 7)) << 4)) = pks;
      *(int4*)((char*)g_sfeat + (size_t)p * 128 + g * 16) = pks;
    }
    if (l < 48) {
      int pi = l / 3, j = l - pi * 3;
      int pp = pid0 + pi;
      out_xyz[(size_t)pp * 3 + j] =
          xyz[((size_t)(pp >> 13) * N_ + idx_fps[pp]) * 3 + j];
    }
  }
  f32x4 qa1[2];
  qa1[0] = (f32x4){0, 0, 0, 0}; qa1[1] = (f32x4){0, 0, 0, 0};
  {
    s16x8 fS[2], fQ;
    #pragma unroll
    for (int ks = 0; ks < 2; ++ks)
      fS[ks] = *(const s16x8*)(buf0 + r * 128 + (((ks * 4 + cq) ^ (r & 7)) << 4));
    #pragma unroll
    for (int ks = 0; ks < 2; ++ks)
      #pragma unroll
      for (int t = 0; t < 2; ++t) {
        fQ = ldfrag_g8(g_fw + (16 * t + r) * CIN + ks * 32 + cq * 8);
        qa1[t] = mfma16(fS[ks], fQ, qa1[t]);
      }
  }

  // ---- prefetch pair 0 ----
  PF pa = pfetch(feats, xyz, idx_fps, pid0,
                 idx_knn[(size_t)pid0 * K_ + r], cq);
  PF pb = pfetch(feats, xyz, idx_fps, pid0 + 1,
                 idx_knn[(size_t)(pid0 + 1) * K_ + r], cq);
  int nidA = idx_knn[(size_t)(pid0 + 2) * K_ + r];
  int nidB = idx_knn[(size_t)(pid0 + 3) * K_ + r];

  // ---- per-pair loop (8 iterations, 2 points each) ----
  #pragma unroll 1
  for (int ip = 0; ip < 8; ++ip) {
    const int pidA = pid0 + 2 * ip;
    const int pidB = pidA + 1;

    // stage nfeat for both points
    {
      int g0 = cq * 2;
      *(int4*)(buf0 + r * 128 + ((g0 ^ (r & 7)) << 4)) = pack8(pa.f0, pa.f1);
      *(int4*)(buf0 + r * 128 + (((g0 + 1) ^ (r & 7)) << 4)) = pack8(pa.f2, pa.f3);
      *(int4*)(buf1 + r * 128 + ((g0 ^ (r & 7)) << 4)) = pack8(pb.f0, pb.f1);
      *(int4*)(buf1 + r * 128 + (((g0 + 1) ^ (r & 7)) << 4)) = pack8(pb.f2, pb.f3);
    }
    s16x8 fRa = {0, 0, 0, 0, 0, 0, 0, 0};
    s16x8 fRb = {0, 0, 0, 0, 0, 0, 0, 0};
    if (cq == 0) {
      fRa[0] = (short)f2bf(pa.r0); fRa[1] = (short)f2bf(pa.r1);
      fRa[2] = (short)f2bf(pa.r2);
      fRb[0] = (short)f2bf(pb.r0); fRb[1] = (short)f2bf(pb.r1);
      fRb[2] = (short)f2bf(pb.r2);
    }

    // prefetch next pair
    if (ip < 7) {
      pa = pfetch(feats, xyz, idx_fps, pidA + 2, nidA, cq);
      pb = pfetch(feats, xyz, idx_fps, pidB + 2, nidB, cq);
      if (ip < 6) {
        nidA = idx_knn[(size_t)(pidA + 4) * K_ + r];
        nidB = idx_knn[(size_t)(pidB + 4) * K_ + r];
      }
    }

    // A-frags of staged nfeat
    s16x8 fAa[2], fAb[2];
    #pragma unroll
    for (int ks = 0; ks < 2; ++ks) {
      fAa[ks] = *(const s16x8*)(buf0 + r * 128 + (((ks * 4 + cq) ^ (r & 7)) << 4));
      fAb[ks] = *(const s16x8*)(buf1 + r * 128 + (((ks * 4 + cq) ^ (r & 7)) << 4));
    }

    // acc_v = nfeat @ Wv^T  (shared B-frag)
    f32x4 va[8], vb[8];
    #pragma unroll
    for (int t = 0; t < 8; ++t) { va[t] = (f32x4){0,0,0,0}; vb[t] = (f32x4){0,0,0,0}; }
    #pragma unroll
    for (int ks = 0; ks < 2; ++ks)
      #pragma unroll
      for (int t = 0; t < 8; ++t) {
        s16x8 wb = ldw128(lWv, 16 * t + r, ks * 4 + cq);
        va[t] = mfma16(fAa[ks], wb, va[t]);
        vb[t] = mfma16(fAb[ks], wb, vb[t]);
      }

    // za1 = -(nfeat @ Wka1^T)   (2 mid-tiles, shared B)
    f32x4 zaa[2], zab[2];
    zaa[0] = (f32x4){0,0,0,0}; zaa[1] = (f32x4){0,0,0,0};
    zab[0] = (f32x4){0,0,0,0}; zab[1] = (f32x4){0,0,0,0};
    #pragma unroll
    for (int ks = 0; ks < 2; ++ks)
      #pragma unroll
      for (int t = 0; t < 2; ++t) {
        s16x8 wb = ldw128(lWka1, 16 * t + r, ks * 4 + cq);
        zaa[t] = mfma16(fAa[ks], wb, zaa[t]);
        zab[t] = mfma16(fAb[ks], wb, zab[t]);
      }

    // t1 = relu(rel @ Wp1^T) -> buf (both points)
    #pragma unroll
    for (int t = 0; t < 8; ++t) {
      s16x8 wp = *(const s16x8*)((const char*)lWp1 + (16 * t + r) * 16);
      f32x4 z0 = {0, 0, 0, 0}, z1 = {0, 0, 0, 0};
      f32x4 ca = mfma16(fRa, wp, z0);
      f32x4 cb = mfma16(fRb, wp, z1);
      st16(buf0, t, ca, l, cq, true);
      st16(buf1, t, cb, l, cq, true);
    }
    s16x8 fTa[4], fTb[4];
    #pragma unroll
    for (int ks = 0; ks < 4; ++ks) {
      fTa[ks] = *(const s16x8*)(buf0 + r * 256 + (((ks * 4 + cq) ^ (r & 7)) << 4));
      fTb[ks] = *(const s16x8*)(buf1 + r * 256 + (((ks * 4 + cq) ^ (r & 7)) << 4));
    }

    // acc_v += pe = t1 @ Wp2^T  (shared B)
    #pragma unroll
    for (int ks = 0; ks < 4; ++ks)
      #pragma unroll
      for (int t = 0; t < 8; ++t) {
        s16x8 wb = ldw256(lWp2, 16 * t + r, ks * 4 + cq);
        va[t] = mfma16(fTa[ks], wb, va[t]);
        vb[t] = mfma16(fTb[ks], wb, vb[t]);
      }

    // za1 += t1 @ Wpa1^T  (shared B)
    #pragma unroll
    for (int ks = 0; ks < 4; ++ks)
      #pragma unroll
      for (int t = 0; t < 2; ++t) {
        s16x8 wb = ldw256(lWpa1, 16 * t + r, ks * 4 + cq);
        zaa[t] = mfma16(fTa[ks], wb, zaa[t]);
        zab[t] = mfma16(fTb[ks], wb, zab[t]);
      }

    // za1 += qa1 broadcast; relu; -> a1 buf
    {
      const int ja = 2 * ip, jb = 2 * ip + 1;
      const int iia = ja & 3, iqa = ja >> 2;
      const int iib = jb & 3, iqb = jb >> 2;
      #pragma unroll
      for (int t = 0; t < 2; ++t) {
        float qsa = iia == 0 ? qa1[t][0] : iia == 1 ? qa1[t][1]
                  : iia == 2 ? qa1[t][2] : qa1[t][3];
        float qva = __shfl(qsa, (iqa << 4) + (l & 15));
        float qsb = iib == 0 ? qa1[t][0] : iib == 1 ? qa1[t][1]
                  : iib == 2 ? qa1[t][2] : qa1[t][3];
        float qvb = __shfl(qsb, (iqb << 4) + (l & 15));
        f32x4 ta = zaa[t], tb = zab[t];
        #pragma unroll
        for (int rr = 0; rr < 4; ++rr) { ta[rr] += qva; tb[rr] += qvb; }
        st16_a1(bufa0, t, ta, l, cq);
        st16_a1(bufa1, t, tb, l, cq);
      }
    }
    // w = a1 @ Wa2^T
    s16x8 fA1a = *(const s16x8*)(bufa0 + r * 64 + ((cq ^ (r & 3)) << 4));
    s16x8 fA1b = *(const s16x8*)(bufa1 + r * 64 + ((cq ^ (r & 3)) << 4));
    f32x4 wwa[8], wwb[8];
    #pragma unroll
    for (int t = 0; t < 8; ++t) {
      f32x4 z0 = {0, 0, 0, 0}, z1 = {0, 0, 0, 0};
      wwa[t] = mfma16(fA1a, fWa2[t], z0);
      wwb[t] = mfma16(fA1b, fWa2[t], z1);
    }
    // softmax over neighbors (rows) + weighted sum of vpe, both points
    #pragma unroll
    for (int t = 0; t < 8; ++t) {
      float ma = fmaxf(fmaxf(wwa[t][0], wwa[t][1]), fmaxf(wwa[t][2], wwa[t][3]));
      float mb = fmaxf(fmaxf(wwb[t][0], wwb[t][1]), fmaxf(wwb[t][2], wwb[t][3]));
      ma = fmaxf(ma, __shfl_xor(ma, 16)); mb = fmaxf(mb, __shfl_xor(mb, 16));
      ma = fmaxf(ma, __shfl_xor(ma, 32)); mb = fmaxf(mb, __shfl_xor(mb, 32));
      float ea0 = __expf(wwa[t][0] - ma), ea1 = __expf(wwa[t][1] - ma);
      float ea2 = __expf(wwa[t][2] - ma), ea3 = __expf(wwa[t][3] - ma);
      float eb0 = __expf(wwb[t][0] - mb), eb1 = __expf(wwb[t][1] - mb);
      float eb2 = __expf(wwb[t][2] - mb), eb3 = __expf(wwb[t][3] - mb);
      float ssa = ea0 + ea1 + ea2 + ea3;
      float ssb = eb0 + eb1 + eb2 + eb3;
      ssa += __shfl_xor(ssa, 16); ssb += __shfl_xor(ssb, 16);
      ssa += __shfl_xor(ssa, 32); ssb += __shfl_xor(ssb, 32);
      float aca = ea0 * va[t][0] + ea1 * va[t][1] + ea2 * va[t][2] + ea3 * va[t][3];
      float acb = eb0 * vb[t][0] + eb1 * vb[t][1] + eb2 * vb[t][2] + eb3 * vb[t][3];
      aca += __shfl_xor(aca, 16); acb += __shfl_xor(acb, 16);
      aca += __shfl_xor(aca, 32); acb += __shfl_xor(acb, 32);
      float oa = aca / ssa;
      float ob = acb / ssb;
      if (cq == (t >> 2)) {
        int colp = (l & 15) + 16 * t;
        *(ushort*)((char*)g_attn + (size_t)pidA * 256 + colp * 2) = f2bf(oa);
        *(ushort*)((char*)g_attn + (size_t)pidB * 256 + colp * 2) = f2bf(ob);
      }
    }
  }
}

// ---------------- Kernel 2: proj + res + LN + post (M = 16 points) ----------
__global__ __launch_bounds__(512, 2) void k_post(
    const float* __restrict__ Wproj, const float* __restrict__ Wres,
    const float* __restrict__ Wpost, const float* __restrict__ ln_w,
    const float* __restrict__ ln_b, float* __restrict__ out_main)
{
  __shared__ ushort lWpj[COUT * COUT];
  __shared__ ushort lWrs[COUT * CIN];
  __shared__ ushort lWps[COUT * COUT];
  __shared__ float  llnw[COUT], llnb[COUT];
  __shared__ ushort sbuf[8 * 16 * COUT];

  const int tid = threadIdx.x;
  const int w = tid >> 6, l = tid & 63;
  const int r = l & 15, cq = l >> 4;

  for (int i = tid; i < COUT * CIN; i += 512) {
    int row = i >> 6; int kp = (i & 63) * 2;
    int g = kp >> 3;
    *(uint*)((char*)lWpj + row * 256 + ((g ^ (row & 7)) << 4) + (kp & 7) * 2)
        = pk2(Wproj[row * COUT + kp], Wproj[row * COUT + kp + 1]);
  }
  for (int i = tid; i < COUT * CIN / 2; i += 512) {
    int row = i >> 5; int kp = (i & 31) * 2;
    int g = kp >> 3;
    *(uint*)((char*)lWrs + row * 128 + ((g ^ (row & 7)) << 4) + (kp & 7) * 2)
        = pk2(Wres[row * CIN + kp], Wres[row * CIN + kp + 1]);
  }
  for (int i = tid; i < COUT * CIN; i += 512) {
    int row = i >> 6; int kp = (i & 63) * 2;
    int g = kp >> 3;
    *(uint*)((char*)lWps + row * 256 + ((g ^ (row & 7)) << 4) + (kp & 7) * 2)
        = pk2(Wpost[row * COUT + kp], Wpost[row * COUT + kp + 1]);
  }
  if (tid < COUT) { llnw[tid] = ln_w[tid]; llnb[tid] = ln_b[tid]; }
  __syncthreads();

  const int T = blockIdx.x * 8 + w;     // 16-point tile id
  char* bufb = (char*)(sbuf + w * 16 * COUT);

  f32x4 acc[8];
  #pragma unroll
  for (int t = 0; t < 8; ++t) acc[t] = (f32x4){0, 0, 0, 0};

  s16x8 fA[4];
  #pragma unroll
  for (int ks = 0; ks < 4; ++ks)
    fA[ks] = *(const s16x8*)(g_attn + ((size_t)T * 16 + r) * COUT + ks * 32 + cq * 8);
  #pragma unroll
  for (int ks = 0; ks < 4; ++ks)
    #pragma unroll
    for (int t = 0; t < 8; ++t)
      acc[t] = mfma16(fA[ks], ldw256(lWpj, 16 * t + r, ks * 4 + cq), acc[t]);

  s16x8 fS[2];
  #pragma unroll
  for (int ks = 0; ks < 2; ++ks)
    fS[ks] = *(const s16x8*)(g_sfeat + ((size_t)T * 16 + r) * CIN + ks * 32 + cq * 8);
  #pragma unroll
  for (int ks = 0; ks < 2; ++ks)
    #pragma unroll
    for (int t = 0; t < 8; ++t)
      acc[t] = mfma16(fS[ks], ldw128(lWrs, 16 * t + r, ks * 4 + cq), acc[t]);

  // LayerNorm per row (= point)
  #pragma unroll
  for (int rr = 0; rr < 4; ++rr) {
    float s1 = 0.f, s2 = 0.f;
    #pragma unroll
    for (int t = 0; t < 8; ++t) { float v = acc[t][rr]; s1 += v; s2 += v * v; }
    #pragma unroll
    for (int off = 1; off < 16; off <<= 1) {
      s1 += __shfl_xor(s1, off);
      s2 += __shfl_xor(s2, off);
    }
    float mu = s1 * (1.f / COUT);
    float rs = rsqrtf(s2 * (1.f / COUT) - mu * mu + EPS_);
    #pragma unroll
    for (int t = 0; t < 8; ++t) {
      int col = (l & 15) + 16 * t;
      acc[t][rr] = (acc[t][rr] - mu) * rs * llnw[col] + llnb[col];
    }
  }
  #pragma unroll
  for (int t = 0; t < 8; ++t) st16(bufb, t, acc[t], l, cq, false);

  // post conv GEMM
  s16x8 fZ[4];
  #pragma unroll
  for (int ks = 0; ks < 4; ++ks)
    fZ[ks] = *(const s16x8*)(bufb + r * 256 + (((ks * 4 + cq) ^ (r & 7)) << 4));
  f32x4 po[8];
  #pragma unroll
  for (int t = 0; t < 8; ++t) po[t] = (f32x4){0, 0, 0, 0};
  #pragma unroll
  for (int ks = 0; ks < 4; ++ks)
    #pragma unroll
    for (int t = 0; t < 8; ++t)
      po[t] = mfma16(fZ[ks], ldw256(lWps, 16 * t + r, ks * 4 + cq), po[t]);

  // write pre-GN post + per-tile GN partials (group = tile t)
  #pragma unroll
  for (int t = 0; t < 8; ++t) {
    float s1 = po[t][0] + po[t][1] + po[t][2] + po[t][3];
    float s2 = po[t][0] * po[t][0] + po[t][1] * po[t][1]
             + po[t][2] * po[t][2] + po[t][3] * po[t][3];
    #pragma unroll
    for (int off = 1; off < 64; off <<= 1) {
      s1 += __shfl_xor(s1, off);
      s2 += __shfl_xor(s2, off);
    }
    if (l == 0) {
      g_part[((size_t)T * 8 + t) * 2] = s1;
      g_part[((size_t)T * 8 + t) * 2 + 1] = s2;
    }
    #pragma unroll
    for (int rr = 0; rr < 4; ++rr) {
      int row = T * 16 + cq * 4 + rr;
      out_main[(size_t)row * COUT + (l & 15) + 16 * t] = po[t][rr];
    }
  }
}

// ---------------- GroupNorm finish + apply ----------------------------------
__global__ void k_gn_finish(void) {
  int bg = blockIdx.x;          // 0..31  (b*8+g)
  int b = bg >> 3, g = bg & 7;
  int t = threadIdx.x;          // 64
  float s1 = 0.f, s2 = 0.f;
  for (int i = t; i < 512; i += 64) {
    size_t T = (size_t)b * 512 + i;
    s1 += g_part[(T * 8 + g) * 2];
    s2 += g_part[(T * 8 + g) * 2 + 1];
  }
  #pragma unroll
  for (int off = 1; off < 64; off <<= 1) {
    s1 += __shfl_xor(s1, off);
    s2 += __shfl_xor(s2, off);
  }
  if (t == 0) {
    float n = (float)S_ * 16.f;
    float mu = s1 / n;
    float var = s2 / n - mu * mu;
    g_stats[bg * 2] = mu;
    g_stats[bg * 2 + 1] = rsqrtf(var + EPS_);
  }
}

__global__ __launch_bounds__(256) void k_gn_apply(
    float* __restrict__ x, const float* __restrict__ gn_w,
    const float* __restrict__ gn_b)
{
  const int i = blockIdx.x * 256 + threadIdx.x;   // float4 index
  if (i >= B_ * S_ * (COUT / 4)) return;
  const int c = (i & 31) * 4;
  const int g = c >> 4;
  const int b = i >> 18;
  const float m = g_stats[(b * 8 + g) * 2];
  const float rv = g_stats[(b * 8 + g) * 2 + 1];
  float4 v = ((float4*)x)[i];
  v.x = fmaxf((v.x - m) * rv * gn_w[c + 0] + gn_b[c + 0], 0.f);
  v.y = fmaxf((v.y - m) * rv * gn_w[c + 1] + gn_b[c + 1], 0.f);
  v.z = fmaxf((v.z - m) * rv * gn_w[c + 2] + gn_b[c + 2], 0.f);
  v.w = fmaxf((v.w - m) * rv * gn_w[c + 3] + gn_b[c + 3], 0.f);
  ((float4*)x)[i] = v;
}

extern "C" void kernel_launch(void* const* d_in, const int* in_sizes, int n_in,
                              void* d_out, int out_size, void* d_ws, size_t ws_size,
                              hipStream_t stream) {
  const float* xyz     = (const float*)d_in[0];
  const float* feats   = (const float*)d_in[1];
  const int*   idx_fps = (const int*)d_in[2];
  const int*   idx_knn = (const int*)d_in[3];
  const float* Wq    = (const float*)d_in[4];
  const float* Wk    = (const float*)d_in[5];
  const float* Wv    = (const float*)d_in[6];
  const float* Wp1   = (const float*)d_in[7];
  const float* Wp2   = (const float*)d_in[8];
  const float* Wa1   = (const float*)d_in[9];
  const float* Wa2   = (const float*)d_in[10];
  const float* Wproj = (const float*)d_in[11];
  const float* ln_w  = (const float*)d_in[12];
  const float* ln_b  = (const float*)d_in[13];
  const float* Wres  = (const float*)d_in[14];
  const float* Wpost = (const float*)d_in[15];
  const float* gn_w  = (const float*)d_in[16];
  const float* gn_b  = (const float*)d_in[17];

  float* out      = (float*)d_out;
  float* out_xyz  = out;
  float* out_main = out + (size_t)B_ * S_ * 3;

  k_fuse<<<dim3(32), dim3(256), 0, stream>>>(Wq, Wk, Wp2, Wa1);
  k_attn<<<dim3(256), dim3(512), 0, stream>>>(
      xyz, feats, idx_fps, idx_knn, Wv, Wp1, Wp2, Wa2, out_xyz);
  k_post<<<dim3(256), dim3(512), 0, stream>>>(
      Wproj, Wres, Wpost, ln_w, ln_b, out_main);
  k_gn_finish<<<dim3(32), dim3(64), 0, stream>>>();
  k_gn_apply<<<dim3((B_ * S_ * (COUT / 4) + 255) / 256), dim3(256), 0, stream>>>(
      out_main, gn_w, gn_b);
}

// Round 6
// 129.778 us; speedup vs baseline: 1.3227x; 1.3227x over previous
//
#include <hip/hip_runtime.h>
#include <hip/hip_bf16.h>
#include <math.h>

#define B_ 4
#define N_ 32768
#define S_ 8192
#define K_ 16
#define CIN 64
#define COUT 128
#define MID_ 32
#define EPS_ 1e-5f
#define NTILE 2048   // (B_*S_)/16 epilogue tiles

typedef __attribute__((ext_vector_type(8))) short s16x8;
typedef __attribute__((ext_vector_type(4))) float f32x4;

// static scratch (written fully every call before being read)
__device__ ushort g_attn[(size_t)B_ * S_ * COUT];   // attn output, bf16, row-major
__device__ ushort g_sfeat[(size_t)B_ * S_ * CIN];   // gathered s_feat, bf16
__device__ float  g_part[NTILE * 8 * 2];            // GN partial sums per tile/group
__device__ float  g_stats[64];                      // GN mean/rstd per (b,g)
// fused weights: [0,2048) Wqa1 32x64; [2048,4096) Wka1 32x64; [4096,8192) Wpa1 32x128
__device__ float  g_fw[8192];

// hardware bf16 converts (v_cvt_pk_bf16_f32)
__device__ __forceinline__ uint pk2(float lo, float hi) {
  __hip_bfloat162 h = __float22bfloat162_rn(make_float2(lo, hi));
  return *(uint*)&h;
}
__device__ __forceinline__ ushort f2bf(float f) {
  __hip_bfloat16 h = __float2bfloat16(f);
  return *(ushort*)&h;
}
__device__ __forceinline__ int4 pack8(float4 a, float4 b) {
  int4 o;
  o.x = pk2(a.x, a.y); o.y = pk2(a.z, a.w);
  o.z = pk2(b.x, b.y); o.w = pk2(b.z, b.w);
  return o;
}
__device__ __forceinline__ f32x4 mfma16(s16x8 a, s16x8 b, f32x4 c) {
  return __builtin_amdgcn_mfma_f32_16x16x32_bf16(a, b, c, 0, 0, 0);
}
// weight B-frag reads, swizzled rows of 256B / 128B / 64B
__device__ __forceinline__ s16x8 ldw256(const ushort* W, int row, int g) {
  return *(const s16x8*)((const char*)W + row * 256 + ((g ^ (row & 7)) << 4));
}
__device__ __forceinline__ s16x8 ldw128(const ushort* W, int row, int g) {
  return *(const s16x8*)((const char*)W + row * 128 + ((g ^ (row & 7)) << 4));
}
__device__ __forceinline__ s16x8 ldw64(const ushort* W, int row, int g) {
  return *(const s16x8*)((const char*)W + row * 64 + ((g ^ (row & 3)) << 4));
}
__device__ __forceinline__ s16x8 ldfrag_g8(const float* p) {
  float4 a = *(const float4*)p, b = *(const float4*)(p + 4);
  union { int4 i; s16x8 s; } u;
  u.i = pack8(a, b);
  return u.s;
}
// store a C tile (16 cols at n-tile t) bf16 into 16x128 swizzled buffer, b16 writes
__device__ __forceinline__ void st16(char* bufb, int t, f32x4 c, int l, int cq,
                                     bool dorelu) {
  const int colp = (l & 15) + 16 * t;
  const int g = colp >> 3;
  const int off = (colp & 7) * 2;
  #pragma unroll
  for (int rr = 0; rr < 4; ++rr) {
    const int row = cq * 4 + rr;
    float v = dorelu ? fmaxf(c[rr], 0.f) : c[rr];
    *(ushort*)(bufb + row * 256 + ((g ^ (row & 7)) << 4) + off) = f2bf(v);
  }
}
// store 16x32 a1 tile (row stride 64B) with relu, b16 writes
__device__ __forceinline__ void st16_a1(char* bufb, int t, f32x4 c, int l, int cq) {
  const int colp = (l & 15) + 16 * t;   // 0..31
  const int g = colp >> 3;              // 0..3
  const int off = (colp & 7) * 2;
  #pragma unroll
  for (int rr = 0; rr < 4; ++rr) {
    const int row = cq * 4 + rr;
    *(ushort*)(bufb + row * 64 + ((g ^ (row & 3)) << 4) + off) =
        f2bf(fmaxf(c[rr], 0.f));
  }
}

struct PF { float4 f0, f1, f2, f3; float r0, r1, r2; };
__device__ __forceinline__ PF pfetch(const float* feats, const float* xyz,
                                     const int* idx_fps, int pid, int nid, int cq) {
  PF p;
  const int bb = pid >> 13;
  const float* fn = feats + ((size_t)bb * N_ + nid) * CIN + cq * 16;
  p.f0 = ((const float4*)fn)[0]; p.f1 = ((const float4*)fn)[1];
  p.f2 = ((const float4*)fn)[2]; p.f3 = ((const float4*)fn)[3];
  p.r0 = 0.f; p.r1 = 0.f; p.r2 = 0.f;
  if (cq == 0) {
    const float* xn = xyz + ((size_t)bb * N_ + nid) * 3;
    const float* xs = xyz + ((size_t)bb * N_ + idx_fps[pid]) * 3;
    p.r0 = xn[0] - xs[0]; p.r1 = xn[1] - xs[1]; p.r2 = xn[2] - xs[2];
  }
  return p;
}

// ---------------- Kernel 0: fused weights  Wa1 @ {Wq, Wk, Wp2} ---------------
__global__ __launch_bounds__(256) void k_fuse(
    const float* __restrict__ Wq, const float* __restrict__ Wk,
    const float* __restrict__ Wp2, const float* __restrict__ Wa1)
{
  const int t = blockIdx.x * 256 + threadIdx.x;   // 0..8191
  if (t < 2048) {
    int m = t >> 6, c = t & 63;
    float s = 0.f;
    for (int o = 0; o < COUT; ++o) s += Wa1[m * COUT + o] * Wq[o * CIN + c];
    g_fw[t] = s;
  } else if (t < 4096) {
    int u = t - 2048;
    int m = u >> 6, c = u & 63;
    float s = 0.f;
    for (int o = 0; o < COUT; ++o) s += Wa1[m * COUT + o] * Wk[o * CIN + c];
    g_fw[t] = s;
  } else {
    int u = t - 4096;
    int m = u >> 7, c = u & 127;
    float s = 0.f;
    for (int o = 0; o < COUT; ++o) s += Wa1[m * COUT + o] * Wp2[o * COUT + c];
    g_fw[t] = s;
  }
}

// ---------------- Kernel 1: attention core (P=2 points per iteration) -------
__global__ __launch_bounds__(512, 2) void k_attn(
    const float* __restrict__ xyz, const float* __restrict__ feats,
    const int* __restrict__ idx_fps, const int* __restrict__ idx_knn,
    const float* __restrict__ Wv, const float* __restrict__ Wp1,
    const float* __restrict__ Wp2, const float* __restrict__ Wa2,
    float* __restrict__ out_xyz)
{
  __shared__ ushort lWv[COUT * CIN];     // 16 KB, 128B rows swz
  __shared__ ushort lWp1[COUT * 8];      // 2 KB, 16B rows linear
  __shared__ ushort lWp2[COUT * COUT];   // 32 KB, 256B rows swz
  __shared__ ushort lWka1[MID_ * CIN];   // 4 KB, 128B rows swz (holds -Wka1)
  __shared__ ushort lWpa1[MID_ * COUT];  // 8 KB, 256B rows swz
  __shared__ ushort lWa2[COUT * MID_];   // 2 KB, 64B rows swz
  __shared__ ushort sbuf[8 * 5120];      // per wave 10KB: 2x4KB nfeat/t1 + 2x1KB a1

  const int tid = threadIdx.x;
  const int w = tid >> 6, l = tid & 63;
  const int r = l & 15, cq = l >> 4;

  for (int i = tid; i < COUT * CIN / 2; i += 512) {
    int row = i >> 5; int kp = (i & 31) * 2;
    int g = kp >> 3;
    *(uint*)((char*)lWv + row * 128 + ((g ^ (row & 7)) << 4) + (kp & 7) * 2)
        = pk2(Wv[row * CIN + kp], Wv[row * CIN + kp + 1]);
  }
  { // Wp1 padded: 128 rows x 4 pairs = 512
    int row = tid >> 2; int kp = (tid & 3) * 2;
    float lo = (kp < 3) ? Wp1[row * 3 + kp] : 0.f;
    float hi = (kp + 1 < 3) ? Wp1[row * 3 + kp + 1] : 0.f;
    *(uint*)((char*)lWp1 + row * 16 + kp * 2) = pk2(lo, hi);
  }
  for (int i = tid; i < COUT * CIN; i += 512) {
    int row = i >> 6; int kp = (i & 63) * 2;
    int g = kp >> 3;
    *(uint*)((char*)lWp2 + row * 256 + ((g ^ (row & 7)) << 4) + (kp & 7) * 2)
        = pk2(Wp2[row * COUT + kp], Wp2[row * COUT + kp + 1]);
  }
  for (int i = tid; i < MID_ * CIN / 2; i += 512) {   // -Wka1
    int row = i >> 5; int kp = (i & 31) * 2;
    int g = kp >> 3;
    const float* src = g_fw + 2048 + row * CIN + kp;
    *(uint*)((char*)lWka1 + row * 128 + ((g ^ (row & 7)) << 4) + (kp & 7) * 2)
        = pk2(-src[0], -src[1]);
  }
  for (int i = tid; i < MID_ * COUT / 2; i += 512) {  // Wpa1
    int row = i >> 6; int kp = (i & 63) * 2;
    int g = kp >> 3;
    const float* src = g_fw + 4096 + row * COUT + kp;
    *(uint*)((char*)lWpa1 + row * 256 + ((g ^ (row & 7)) << 4) + (kp & 7) * 2)
        = pk2(src[0], src[1]);
  }
  for (int i = tid; i < COUT * MID_ / 2; i += 512) {  // Wa2: 128 rows x 16 pairs
    int row = i >> 4; int kp = (i & 15) * 2;
    int g = kp >> 3;
    *(uint*)((char*)lWa2 + row * 64 + ((g ^ (row & 3)) << 4) + (kp & 7) * 2)
        = pk2(Wa2[row * MID_ + kp], Wa2[row * MID_ + kp + 1]);
  }

  __syncthreads();

  char* bufb = (char*)(sbuf + w * 5120);
  char* buf0 = bufb;
  char* buf1 = bufb + 4096;
  char* bufa0 = bufb + 8192;
  char* bufa1 = bufb + 9216;
  const int pid0 = (blockIdx.x * 8 + w) * 16;

  // ---- prologue: stage sfeat (row = point), qa1 GEMM for 16 points ----
  {
    const int p = pid0 + r;
    const int bb = p >> 13;
    const int si = idx_fps[p];
    const float* fs = feats + ((size_t)bb * N_ + si) * CIN;
    #pragma unroll
    for (int j = 0; j < 2; ++j) {
      int g = cq * 2 + j;
      int4 pks = pack8(*(const float4*)(fs + g * 8), *(const float4*)(fs + g * 8 + 4));
      *(int4*)(buf0 + r * 128 + ((g ^ (r & 7)) << 4)) = pks;
      *(int4*)((char*)g_sfeat + (size_t)p * 128 + g * 16) = pks;
    }
    if (l < 48) {
      int pi = l / 3, j = l - pi * 3;
      int pp = pid0 + pi;
      out_xyz[(size_t)pp * 3 + j] =
          xyz[((size_t)(pp >> 13) * N_ + idx_fps[pp]) * 3 + j];
    }
  }
  f32x4 qa1[2];
  qa1[0] = (f32x4){0, 0, 0, 0}; qa1[1] = (f32x4){0, 0, 0, 0};
  {
    s16x8 fS[2], fQ;
    #pragma unroll
    for (int ks = 0; ks < 2; ++ks)
      fS[ks] = *(const s16x8*)(buf0 + r * 128 + (((ks * 4 + cq) ^ (r & 7)) << 4));
    #pragma unroll
    for (int ks = 0; ks < 2; ++ks)
      #pragma unroll
      for (int t = 0; t < 2; ++t) {
        fQ = ldfrag_g8(g_fw + (16 * t + r) * CIN + ks * 32 + cq * 8);
        qa1[t] = mfma16(fS[ks], fQ, qa1[t]);
      }
  }

  // ---- prefetch pair 0 ----
  PF pa = pfetch(feats, xyz, idx_fps, pid0,
                 idx_knn[(size_t)pid0 * K_ + r], cq);
  PF pb = pfetch(feats, xyz, idx_fps, pid0 + 1,
                 idx_knn[(size_t)(pid0 + 1) * K_ + r], cq);
  int nidA = idx_knn[(size_t)(pid0 + 2) * K_ + r];
  int nidB = idx_knn[(size_t)(pid0 + 3) * K_ + r];

  // ---- per-pair loop (8 iterations, 2 points each) ----
  #pragma unroll 1
  for (int ip = 0; ip < 8; ++ip) {
    const int pidA = pid0 + 2 * ip;
    const int pidB = pidA + 1;

    // stage nfeat for both points
    {
      int g0 = cq * 2;
      *(int4*)(buf0 + r * 128 + ((g0 ^ (r & 7)) << 4)) = pack8(pa.f0, pa.f1);
      *(int4*)(buf0 + r * 128 + (((g0 + 1) ^ (r & 7)) << 4)) = pack8(pa.f2, pa.f3);
      *(int4*)(buf1 + r * 128 + ((g0 ^ (r & 7)) << 4)) = pack8(pb.f0, pb.f1);
      *(int4*)(buf1 + r * 128 + (((g0 + 1) ^ (r & 7)) << 4)) = pack8(pb.f2, pb.f3);
    }
    s16x8 fRa = {0, 0, 0, 0, 0, 0, 0, 0};
    s16x8 fRb = {0, 0, 0, 0, 0, 0, 0, 0};
    if (cq == 0) {
      fRa[0] = (short)f2bf(pa.r0); fRa[1] = (short)f2bf(pa.r1);
      fRa[2] = (short)f2bf(pa.r2);
      fRb[0] = (short)f2bf(pb.r0); fRb[1] = (short)f2bf(pb.r1);
      fRb[2] = (short)f2bf(pb.r2);
    }

    // prefetch next pair
    if (ip < 7) {
      pa = pfetch(feats, xyz, idx_fps, pidA + 2, nidA, cq);
      pb = pfetch(feats, xyz, idx_fps, pidB + 2, nidB, cq);
      if (ip < 6) {
        nidA = idx_knn[(size_t)(pidA + 4) * K_ + r];
        nidB = idx_knn[(size_t)(pidB + 4) * K_ + r];
      }
    }

    // A-frags of staged nfeat
    s16x8 fAa[2], fAb[2];
    #pragma unroll
    for (int ks = 0; ks < 2; ++ks) {
      fAa[ks] = *(const s16x8*)(buf0 + r * 128 + (((ks * 4 + cq) ^ (r & 7)) << 4));
      fAb[ks] = *(const s16x8*)(buf1 + r * 128 + (((ks * 4 + cq) ^ (r & 7)) << 4));
    }

    // acc_v = nfeat @ Wv^T  (shared B-frag)
    f32x4 va[8], vb[8];
    #pragma unroll
    for (int t = 0; t < 8; ++t) { va[t] = (f32x4){0,0,0,0}; vb[t] = (f32x4){0,0,0,0}; }
    #pragma unroll
    for (int ks = 0; ks < 2; ++ks)
      #pragma unroll
      for (int t = 0; t < 8; ++t) {
        s16x8 wb = ldw128(lWv, 16 * t + r, ks * 4 + cq);
        va[t] = mfma16(fAa[ks], wb, va[t]);
        vb[t] = mfma16(fAb[ks], wb, vb[t]);
      }

    // za1 = -(nfeat @ Wka1^T)   (2 mid-tiles, shared B)
    f32x4 zaa[2], zab[2];
    zaa[0] = (f32x4){0,0,0,0}; zaa[1] = (f32x4){0,0,0,0};
    zab[0] = (f32x4){0,0,0,0}; zab[1] = (f32x4){0,0,0,0};
    #pragma unroll
    for (int ks = 0; ks < 2; ++ks)
      #pragma unroll
      for (int t = 0; t < 2; ++t) {
        s16x8 wb = ldw128(lWka1, 16 * t + r, ks * 4 + cq);
        zaa[t] = mfma16(fAa[ks], wb, zaa[t]);
        zab[t] = mfma16(fAb[ks], wb, zab[t]);
      }

    // t1 = relu(rel @ Wp1^T) -> buf (both points)
    #pragma unroll
    for (int t = 0; t < 8; ++t) {
      s16x8 wp = *(const s16x8*)((const char*)lWp1 + (16 * t + r) * 16);
      f32x4 z0 = {0, 0, 0, 0}, z1 = {0, 0, 0, 0};
      f32x4 ca = mfma16(fRa, wp, z0);
      f32x4 cb = mfma16(fRb, wp, z1);
      st16(buf0, t, ca, l, cq, true);
      st16(buf1, t, cb, l, cq, true);
    }
    s16x8 fTa[4], fTb[4];
    #pragma unroll
    for (int ks = 0; ks < 4; ++ks) {
      fTa[ks] = *(const s16x8*)(buf0 + r * 256 + (((ks * 4 + cq) ^ (r & 7)) << 4));
      fTb[ks] = *(const s16x8*)(buf1 + r * 256 + (((ks * 4 + cq) ^ (r & 7)) << 4));
    }

    // acc_v += pe = t1 @ Wp2^T  (shared B)
    #pragma unroll
    for (int ks = 0; ks < 4; ++ks)
      #pragma unroll
      for (int t = 0; t < 8; ++t) {
        s16x8 wb = ldw256(lWp2, 16 * t + r, ks * 4 + cq);
        va[t] = mfma16(fTa[ks], wb, va[t]);
        vb[t] = mfma16(fTb[ks], wb, vb[t]);
      }

    // za1 += t1 @ Wpa1^T  (shared B)
    #pragma unroll
    for (int ks = 0; ks < 4; ++ks)
      #pragma unroll
      for (int t = 0; t < 2; ++t) {
        s16x8 wb = ldw256(lWpa1, 16 * t + r, ks * 4 + cq);
        zaa[t] = mfma16(fTa[ks], wb, zaa[t]);
        zab[t] = mfma16(fTb[ks], wb, zab[t]);
      }

    // za1 += qa1 broadcast; relu; -> a1 buf
    {
      const int ja = 2 * ip, jb = 2 * ip + 1;
      const int iia = ja & 3, iqa = ja >> 2;
      const int iib = jb & 3, iqb = jb >> 2;
      #pragma unroll
      for (int t = 0; t < 2; ++t) {
        float qsa = iia == 0 ? qa1[t][0] : iia == 1 ? qa1[t][1]
                  : iia == 2 ? qa1[t][2] : qa1[t][3];
        float qva = __shfl(qsa, (iqa << 4) + (l & 15));
        float qsb = iib == 0 ? qa1[t][0] : iib == 1 ? qa1[t][1]
                  : iib == 2 ? qa1[t][2] : qa1[t][3];
        float qvb = __shfl(qsb, (iqb << 4) + (l & 15));
        f32x4 ta = zaa[t], tb = zab[t];
        #pragma unroll
        for (int rr = 0; rr < 4; ++rr) { ta[rr] += qva; tb[rr] += qvb; }
        st16_a1(bufa0, t, ta, l, cq);
        st16_a1(bufa1, t, tb, l, cq);
      }
    }
    // w = a1 @ Wa2^T  (shared B from LDS)
    s16x8 fA1a = *(const s16x8*)(bufa0 + r * 64 + ((cq ^ (r & 3)) << 4));
    s16x8 fA1b = *(const s16x8*)(bufa1 + r * 64 + ((cq ^ (r & 3)) << 4));
    f32x4 wwa[8], wwb[8];
    #pragma unroll
    for (int t = 0; t < 8; ++t) {
      s16x8 wb2 = ldw64(lWa2, 16 * t + r, cq);
      f32x4 z0 = {0, 0, 0, 0}, z1 = {0, 0, 0, 0};
      wwa[t] = mfma16(fA1a, wb2, z0);
      wwb[t] = mfma16(fA1b, wb2, z1);
    }
    // softmax over neighbors (rows) + weighted sum of vpe, both points
    #pragma unroll
    for (int t = 0; t < 8; ++t) {
      float ma = fmaxf(fmaxf(wwa[t][0], wwa[t][1]), fmaxf(wwa[t][2], wwa[t][3]));
      float mb = fmaxf(fmaxf(wwb[t][0], wwb[t][1]), fmaxf(wwb[t][2], wwb[t][3]));
      ma = fmaxf(ma, __shfl_xor(ma, 16)); mb = fmaxf(mb, __shfl_xor(mb, 16));
      ma = fmaxf(ma, __shfl_xor(ma, 32)); mb = fmaxf(mb, __shfl_xor(mb, 32));
      float ea0 = __expf(wwa[t][0] - ma), ea1 = __expf(wwa[t][1] - ma);
      float ea2 = __expf(wwa[t][2] - ma), ea3 = __expf(wwa[t][3] - ma);
      float eb0 = __expf(wwb[t][0] - mb), eb1 = __expf(wwb[t][1] - mb);
      float eb2 = __expf(wwb[t][2] - mb), eb3 = __expf(wwb[t][3] - mb);
      float ssa = ea0 + ea1 + ea2 + ea3;
      float ssb = eb0 + eb1 + eb2 + eb3;
      ssa += __shfl_xor(ssa, 16); ssb += __shfl_xor(ssb, 16);
      ssa += __shfl_xor(ssa, 32); ssb += __shfl_xor(ssb, 32);
      float aca = ea0 * va[t][0] + ea1 * va[t][1] + ea2 * va[t][2] + ea3 * va[t][3];
      float acb = eb0 * vb[t][0] + eb1 * vb[t][1] + eb2 * vb[t][2] + eb3 * vb[t][3];
      aca += __shfl_xor(aca, 16); acb += __shfl_xor(acb, 16);
      aca += __shfl_xor(aca, 32); acb += __shfl_xor(acb, 32);
      float oa = aca / ssa;
      float ob = acb / ssb;
      if (cq == (t >> 2)) {
        int colp = (l & 15) + 16 * t;
        *(ushort*)((char*)g_attn + (size_t)pidA * 256 + colp * 2) = f2bf(oa);
        *(ushort*)((char*)g_attn + (size_t)pidB * 256 + colp * 2) = f2bf(ob);
      }
    }
  }
}

// ---------------- Kernel 2: proj + res + LN + post (M = 16 points) ----------
__global__ __launch_bounds__(512, 2) void k_post(
    const float* __restrict__ Wproj, const float* __restrict__ Wres,
    const float* __restrict__ Wpost, const float* __restrict__ ln_w,
    const float* __restrict__ ln_b, float* __restrict__ out_main)
{
  __shared__ ushort lWpj[COUT * COUT];
  __shared__ ushort lWrs[COUT * CIN];
  __shared__ ushort lWps[COUT * COUT];
  __shared__ float  llnw[COUT], llnb[COUT];
  __shared__ ushort sbuf[8 * 16 * COUT];

  const int tid = threadIdx.x;
  const int w = tid >> 6, l = tid & 63;
  const int r = l & 15, cq = l >> 4;

  for (int i = tid; i < COUT * CIN; i += 512) {
    int row = i >> 6; int kp = (i & 63) * 2;
    int g = kp >> 3;
    *(uint*)((char*)lWpj + row * 256 + ((g ^ (row & 7)) << 4) + (kp & 7) * 2)
        = pk2(Wproj[row * COUT + kp], Wproj[row * COUT + kp + 1]);
  }
  for (int i = tid; i < COUT * CIN / 2; i += 512) {
    int row = i >> 5; int kp = (i & 31) * 2;
    int g = kp >> 3;
    *(uint*)((char*)lWrs + row * 128 + ((g ^ (row & 7)) << 4) + (kp & 7) * 2)
        = pk2(Wres[row * CIN + kp], Wres[row * CIN + kp + 1]);
  }
  for (int i = tid; i < COUT * CIN; i += 512) {
    int row = i >> 6; int kp = (i & 63) * 2;
    int g = kp >> 3;
    *(uint*)((char*)lWps + row * 256 + ((g ^ (row & 7)) << 4) + (kp & 7) * 2)
        = pk2(Wpost[row * COUT + kp], Wpost[row * COUT + kp + 1]);
  }
  if (tid < COUT) { llnw[tid] = ln_w[tid]; llnb[tid] = ln_b[tid]; }
  __syncthreads();

  const int T = blockIdx.x * 8 + w;     // 16-point tile id
  char* bufb = (char*)(sbuf + w * 16 * COUT);

  f32x4 acc[8];
  #pragma unroll
  for (int t = 0; t < 8; ++t) acc[t] = (f32x4){0, 0, 0, 0};

  s16x8 fA[4];
  #pragma unroll
  for (int ks = 0; ks < 4; ++ks)
    fA[ks] = *(const s16x8*)(g_attn + ((size_t)T * 16 + r) * COUT + ks * 32 + cq * 8);
  #pragma unroll
  for (int ks = 0; ks < 4; ++ks)
    #pragma unroll
    for (int t = 0; t < 8; ++t)
      acc[t] = mfma16(fA[ks], ldw256(lWpj, 16 * t + r, ks * 4 + cq), acc[t]);

  s16x8 fS[2];
  #pragma unroll
  for (int ks = 0; ks < 2; ++ks)
    fS[ks] = *(const s16x8*)(g_sfeat + ((size_t)T * 16 + r) * CIN + ks * 32 + cq * 8);
  #pragma unroll
  for (int ks = 0; ks < 2; ++ks)
    #pragma unroll
    for (int t = 0; t < 8; ++t)
      acc[t] = mfma16(fS[ks], ldw128(lWrs, 16 * t + r, ks * 4 + cq), acc[t]);

  // LayerNorm per row (= point)
  #pragma unroll
  for (int rr = 0; rr < 4; ++rr) {
    float s1 = 0.f, s2 = 0.f;
    #pragma unroll
    for (int t = 0; t < 8; ++t) { float v = acc[t][rr]; s1 += v; s2 += v * v; }
    #pragma unroll
    for (int off = 1; off < 16; off <<= 1) {
      s1 += __shfl_xor(s1, off);
      s2 += __shfl_xor(s2, off);
    }
    float mu = s1 * (1.f / COUT);
    float rs = rsqrtf(s2 * (1.f / COUT) - mu * mu + EPS_);
    #pragma unroll
    for (int t = 0; t < 8; ++t) {
      int col = (l & 15) + 16 * t;
      acc[t][rr] = (acc[t][rr] - mu) * rs * llnw[col] + llnb[col];
    }
  }
  #pragma unroll
  for (int t = 0; t < 8; ++t) st16(bufb, t, acc[t], l, cq, false);

  // post conv GEMM
  s16x8 fZ[4];
  #pragma unroll
  for (int ks = 0; ks < 4; ++ks)
    fZ[ks] = *(const s16x8*)(bufb + r * 256 + (((ks * 4 + cq) ^ (r & 7)) << 4));
  f32x4 po[8];
  #pragma unroll
  for (int t = 0; t < 8; ++t) po[t] = (f32x4){0, 0, 0, 0};
  #pragma unroll
  for (int ks = 0; ks < 4; ++ks)
    #pragma unroll
    for (int t = 0; t < 8; ++t)
      po[t] = mfma16(fZ[ks], ldw256(lWps, 16 * t + r, ks * 4 + cq), po[t]);

  // write pre-GN post + per-tile GN partials (group = tile t)
  #pragma unroll
  for (int t = 0; t < 8; ++t) {
    float s1 = po[t][0] + po[t][1] + po[t][2] + po[t][3];
    float s2 = po[t][0] * po[t][0] + po[t][1] * po[t][1]
             + po[t][2] * po[t][2] + po[t][3] * po[t][3];
    #pragma unroll
    for (int off = 1; off < 64; off <<= 1) {
      s1 += __shfl_xor(s1, off);
      s2 += __shfl_xor(s2, off);
    }
    if (l == 0) {
      g_part[((size_t)T * 8 + t) * 2] = s1;
      g_part[((size_t)T * 8 + t) * 2 + 1] = s2;
    }
    #pragma unroll
    for (int rr = 0; rr < 4; ++rr) {
      int row = T * 16 + cq * 4 + rr;
      out_main[(size_t)row * COUT + (l & 15) + 16 * t] = po[t][rr];
    }
  }
}

// ---------------- GroupNorm finish + apply ----------------------------------
__global__ void k_gn_finish(void) {
  int bg = blockIdx.x;          // 0..31  (b*8+g)
  int b = bg >> 3, g = bg & 7;
  int t = threadIdx.x;          // 64
  float s1 = 0.f, s2 = 0.f;
  for (int i = t; i < 512; i += 64) {
    size_t T = (size_t)b * 512 + i;
    s1 += g_part[(T * 8 + g) * 2];
    s2 += g_part[(T * 8 + g) * 2 + 1];
  }
  #pragma unroll
  for (int off = 1; off < 64; off <<= 1) {
    s1 += __shfl_xor(s1, off);
    s2 += __shfl_xor(s2, off);
  }
  if (t == 0) {
    float n = (float)S_ * 16.f;
    float mu = s1 / n;
    float var = s2 / n - mu * mu;
    g_stats[bg * 2] = mu;
    g_stats[bg * 2 + 1] = rsqrtf(var + EPS_);
  }
}

__global__ __launch_bounds__(256) void k_gn_apply(
    float* __restrict__ x, const float* __restrict__ gn_w,
    const float* __restrict__ gn_b)
{
  const int i = blockIdx.x * 256 + threadIdx.x;   // float4 index
  if (i >= B_ * S_ * (COUT / 4)) return;
  const int c = (i & 31) * 4;
  const int g = c >> 4;
  const int b = i >> 18;
  const float m = g_stats[(b * 8 + g) * 2];
  const float rv = g_stats[(b * 8 + g) * 2 + 1];
  float4 v = ((float4*)x)[i];
  v.x = fmaxf((v.x - m) * rv * gn_w[c + 0] + gn_b[c + 0], 0.f);
  v.y = fmaxf((v.y - m) * rv * gn_w[c + 1] + gn_b[c + 1], 0.f);
  v.z = fmaxf((v.z - m) * rv * gn_w[c + 2] + gn_b[c + 2], 0.f);
  v.w = fmaxf((v.w - m) * rv * gn_w[c + 3] + gn_b[c + 3], 0.f);
  ((float4*)x)[i] = v;
}

extern "C" void kernel_launch(void* const* d_in, const int* in_sizes, int n_in,
                              void* d_out, int out_size, void* d_ws, size_t ws_size,
                              hipStream_t stream) {
  const float* xyz     = (const float*)d_in[0];
  const float* feats   = (const float*)d_in[1];
  const int*   idx_fps = (const int*)d_in[2];
  const int*   idx_knn = (const int*)d_in[3];
  const float* Wq    = (const float*)d_in[4];
  const float* Wk    = (const float*)d_in[5];
  const float* Wv    = (const float*)d_in[6];
  const float* Wp1   = (const float*)d_in[7];
  const float* Wp2   = (const float*)d_in[8];
  const float* Wa1   = (const float*)d_in[9];
  const float* Wa2   = (const float*)d_in[10];
  const float* Wproj = (const float*)d_in[11];
  const float* ln_w  = (const float*)d_in[12];
  const float* ln_b  = (const float*)d_in[13];
  const float* Wres  = (const float*)d_in[14];
  const float* Wpost = (const float*)d_in[15];
  const float* gn_w  = (const float*)d_in[16];
  const float* gn_b  = (const float*)d_in[17];

  float* out      = (float*)d_out;
  float* out_xyz  = out;
  float* out_main = out + (size_t)B_ * S_ * 3;

  k_fuse<<<dim3(32), dim3(256), 0, stream>>>(Wq, Wk, Wp2, Wa1);
  k_attn<<<dim3(256), dim3(512), 0, stream>>>(
      xyz, feats, idx_fps, idx_knn, Wv, Wp1, Wp2, Wa2, out_xyz);
  k_post<<<dim3(256), dim3(512), 0, stream>>>(
      Wproj, Wres, Wpost, ln_w, ln_b, out_main);
  k_gn_finish<<<dim3(32), dim3(64), 0, stream>>>();
  k_gn_apply<<<dim3((B_ * S_ * (COUT / 4) + 255) / 256), dim3(256), 0, stream>>>(
      out_main, gn_w, gn_b);
}